// Round 3
// baseline (3033.899 us; speedup 1.0000x reference)
//
#include <hip/hip_runtime.h>
#include <hip/hip_bf16.h>

#define TS 256
#define BB 128
#define II 1024
#define HH 1024
#define PP 512
#define GG 4096  // 4*H
#define NWG 256
#define WPG 64        // WGs per group (hidden tiles)
#define BT 32         // batch rows per group
#define HCW 16        // hidden cols per WG
#define BSTRIDE 1032  // shorts per Bs row (pad 1024+8 to spread banks)
#define RSTRIDE 20    // floats per red row (pad 16+4)
#define SMEM_BYTES (64 * BSTRIDE * 2 + 2 * 64 * RSTRIDE * 4)  // 132096 + 10240 = 142336

typedef __attribute__((ext_vector_type(8))) short bf16x8;
typedef __attribute__((ext_vector_type(4))) float f32x4;

__device__ __forceinline__ short f2bs(float f) {
    __hip_bfloat16 h = __float2bfloat16(f);
    return __builtin_bit_cast(short, h);
}
__device__ __forceinline__ float bs2f(short s) {
    return __bfloat162float(__builtin_bit_cast(__hip_bfloat16, s));
}

__device__ __forceinline__ bf16x8 ld8(const __hip_bfloat16* p) {
    return *(const bf16x8*)p;
}
__device__ __forceinline__ bf16x8 ld8(const float* p) {
    f32x4 lo = *(const f32x4*)p;
    f32x4 hi = *(const f32x4*)(p + 4);
    bf16x8 r;
#pragma unroll
    for (int i = 0; i < 4; ++i) { r[i] = f2bs(lo[i]); r[4 + i] = f2bs(hi[i]); }
    return r;
}

__device__ __forceinline__ void stv(float* p, long i, float v) { p[i] = v; }
__device__ __forceinline__ void stv(__hip_bfloat16* p, long i, float v) { p[i] = __float2bfloat16(v); }

// Write-through bf16 store: sc0 sc1 -> visible at the device coherence point (MALL).
__device__ __forceinline__ void st_bf16_wt(__hip_bfloat16* p, float v) {
    int si = (int)f2bs(v);
    asm volatile("global_store_short %0, %1, off sc0 sc1" :: "v"(p), "v"(si));
}
// Coherence-point 16B load (bypass L1/L2): reads MALL, so no acquire-invalidate needed.
__device__ __forceinline__ f32x4 ld16_mall(const void* p) {
    f32x4 r;
    asm volatile("global_load_dwordx4 %0, %1, off sc0 sc1" : "=&v"(r) : "v"(p));
    return r;
}
// Per-wave drain: all outstanding vmem ops (incl. asm write-through stores) complete.
__device__ __forceinline__ void vm_drain() {
    asm volatile("s_waitcnt vmcnt(0)" ::: "memory");
}

// C[M,N] = A[M,K] @ B[N,K]^T, MFMA bf16. 128x128 tile, BK=32, 4 waves (64x64 each).
template <typename AT, typename BT_, typename CT>
__global__ __launch_bounds__(256) void mfma_gemm_bt(const AT* __restrict__ A,
                                                    const BT_* __restrict__ B,
                                                    CT* __restrict__ C,
                                                    int M, int N, int K) {
    __shared__ __align__(16) short As[128][40];
    __shared__ __align__(16) short Bsh[128][40];
    const int tid = threadIdx.x;
    const long bm = (long)blockIdx.y * 128;
    const long bn = (long)blockIdx.x * 128;
    const int lane = tid & 63, wv = tid >> 6;
    const int l15 = lane & 15, quad = lane >> 4;
    const int wm = (wv >> 1) * 64, wn = (wv & 1) * 64;
    f32x4 acc[4][4] = {};
    for (int k0 = 0; k0 < K; k0 += 32) {
#pragma unroll
        for (int i = 0; i < 2; ++i) {
            int ch = tid + 256 * i;
            int row = ch >> 2, koff = (ch & 3) * 8;
            *(bf16x8*)&As[row][koff] = ld8(&A[(bm + row) * (long)K + k0 + koff]);
            *(bf16x8*)&Bsh[row][koff] = ld8(&B[(bn + row) * (long)K + k0 + koff]);
        }
        __syncthreads();
        bf16x8 af[4], bfv[4];
#pragma unroll
        for (int t = 0; t < 4; ++t) {
            af[t] = *(const bf16x8*)&As[wm + t * 16 + l15][quad * 8];
            bfv[t] = *(const bf16x8*)&Bsh[wn + t * 16 + l15][quad * 8];
        }
#pragma unroll
        for (int mt = 0; mt < 4; ++mt)
#pragma unroll
            for (int nt = 0; nt < 4; ++nt)
                acc[mt][nt] = __builtin_amdgcn_mfma_f32_16x16x32_bf16(af[mt], bfv[nt], acc[mt][nt], 0, 0, 0);
        __syncthreads();
    }
#pragma unroll
    for (int mt = 0; mt < 4; ++mt)
#pragma unroll
        for (int nt = 0; nt < 4; ++nt)
#pragma unroll
            for (int r = 0; r < 4; ++r) {
                long row = bm + wm + mt * 16 + quad * 4 + r;
                long col = bn + wn + nt * 16 + l15;
                stv(C, row * N + col, acc[mt][nt][r]);
            }
}

// Per-wave matmul slice of the recurrence:
//   out[32 batch x 64 gatecols] = A[32 x K] @ Bs[64 x K]^T, waves split (mt, K-half).
// Bs rows ordered [gate g 0..3][hcol h 0..15]; acc[g] = gate g at col l15.
// A loads: ALL issued upfront as coherence-point (sc0 sc1) asm loads, then one
// vmcnt(0) + sched_barrier(0), then pure-register MFMA. Forces single latency
// exposure (the compiler refused this hoist for plain loads: VGPR stayed 72).
template <int K>
__device__ __forceinline__ void rec_mm(const __hip_bfloat16* __restrict__ Abase,
                                       const short* __restrict__ Bs, f32x4* acc,
                                       int l15, int quad, int mt, int kh) {
    constexpr int KH = K / 2;
    constexpr int NI = KH / 32;
    const __hip_bfloat16* ap = Abase + (long)(mt * 16 + l15) * K + kh * KH + quad * 8;
    const short* bp0 = Bs + l15 * BSTRIDE + kh * KH + quad * 8;
    f32x4 avr[NI];
#pragma unroll
    for (int i = 0; i < NI; ++i) avr[i] = ld16_mall(ap + i * 32);
    asm volatile("s_waitcnt vmcnt(0)" ::: "memory");
    __builtin_amdgcn_sched_barrier(0);
#pragma unroll
    for (int i = 0; i < NI; ++i) {
        bf16x8 av = __builtin_bit_cast(bf16x8, avr[i]);
        const short* bp = bp0 + i * 32;
        acc[0] = __builtin_amdgcn_mfma_f32_16x16x32_bf16(av, *(const bf16x8*)(bp), acc[0], 0, 0, 0);
        acc[1] = __builtin_amdgcn_mfma_f32_16x16x32_bf16(av, *(const bf16x8*)(bp + 16 * BSTRIDE), acc[1], 0, 0, 0);
        acc[2] = __builtin_amdgcn_mfma_f32_16x16x32_bf16(av, *(const bf16x8*)(bp + 32 * BSTRIDE), acc[2], 0, 0, 0);
        acc[3] = __builtin_amdgcn_mfma_f32_16x16x32_bf16(av, *(const bf16x8*)(bp + 48 * BSTRIDE), acc[3], 0, 0, 0);
    }
}

// Cooperative recurrence: 4 independent batch-groups x 64 WGs.
// WG = (grp = wg>>6, jj = wg&63): batch rows [32*grp, +32), hidden cols [16*jj, +16).
// Protocol (fence-free):
//   release: write-through hfull stores (sc0 sc1) -> per-wave vmcnt drain ->
//            per-WAVE flag store (2 flags/WG; no cross-wave join on release path).
//   acquire: poll 128 flags (tid<128) -> syncthreads -> A reads are sc0 sc1
//            coherence-point loads (no L2 invalidate anywhere in the loop).
__global__ __launch_bounds__(256) void lstm_rec_k(
    const __hip_bfloat16* __restrict__ h0b,   // [128][512]
    const float* __restrict__ c0,             // [128][1024]
    const float* __restrict__ Whh,            // [4096][512] fp32
    const __hip_bfloat16* __restrict__ Wcomb, // [4096][1024]
    const __hip_bfloat16* __restrict__ xg,    // [256][128][4096]
    __hip_bfloat16* __restrict__ hfull,       // [256][128][1024]
    float* __restrict__ cT,                   // [128][1024]
    unsigned* __restrict__ flags) {           // [4][128]
    extern __shared__ char smem[];
    short* Bs = (short*)smem;                        // [64][BSTRIDE] bf16
    float* red = (float*)(smem + 64 * BSTRIDE * 2);  // [2][64][RSTRIDE] K-split partials

    const int tid = threadIdx.x;
    const int wg = blockIdx.x;
    const int grp = wg >> 6;
    const int jj = wg & 63;
    const int hc0 = jj * HCW;
    const int bt = grp * BT;
    const int lane = tid & 63, wv = tid >> 6;
    const int l15 = lane & 15, quad = lane >> 4;
    const int mt = wv & 1, kh = wv >> 1;
    unsigned* gflag = flags + grp * 2 * WPG;
    const int brow = bt + mt * 16 + quad * 4;  // + r

    // Stage B(t=0): 64 rows (g*16+h) = Whh[g*1024 + hc0 + h][0..512), fp32 -> bf16
    for (int ch = tid; ch < 64 * 64; ch += 256) {
        int row = ch >> 6, koff = (ch & 63) * 8;
        long wr = (long)(row >> 4) * HH + hc0 + (row & 15);
        *(bf16x8*)&Bs[row * BSTRIDE + koff] = ld8(&Whh[wr * PP + koff]);
    }

    float creg[4];
    if (kh == 0) {
#pragma unroll
        for (int r = 0; r < 4; ++r) creg[r] = c0[(long)(brow + r) * HH + hc0 + l15];
    }

    short xr[16];
    auto ldxg = [&](int t) {  // prefetch xg for this step (issued before the flag wait)
        if (kh == 0) {
            const __hip_bfloat16* xgt = xg + (long)t * BB * GG;
#pragma unroll
            for (int g = 0; g < 4; ++g)
#pragma unroll
                for (int r = 0; r < 4; ++r)
                    xr[g * 4 + r] = *(const short*)(xgt + (long)(brow + r) * GG + g * HH + hc0 + l15);
        }
    };

    // K-split reduce + in-register cell + per-wave release (drain + own flag).
    auto finish = [&](f32x4* acc, int t, bool flag) {
        if (kh == 1) {
            float* rp = red + (mt * 64 + lane) * RSTRIDE;
#pragma unroll
            for (int g = 0; g < 4; ++g) *(f32x4*)(rp + g * 4) = acc[g];
        }
        __syncthreads();
        if (kh == 0) {
            const float* rp = red + (mt * 64 + lane) * RSTRIDE;
#pragma unroll
            for (int g = 0; g < 4; ++g) acc[g] += *(const f32x4*)(rp + g * 4);
            __hip_bfloat16* hp = hfull + (long)t * BB * HH;
#pragma unroll
            for (int r = 0; r < 4; ++r) {
                float gi = acc[0][r] + bs2f(xr[r]);
                float gf = acc[1][r] + bs2f(xr[4 + r]);
                float gg = acc[2][r] + bs2f(xr[8 + r]);
                float go = acc[3][r] + bs2f(xr[12 + r]);
                float i_ = 1.f / (1.f + expf(-gi));
                float f_ = 1.f / (1.f + expf(-gf));
                float g_ = tanhf(gg);
                float o_ = 1.f / (1.f + expf(-go));
                float c = f_ * creg[r] + i_ * g_;
                creg[r] = c;
                st_bf16_wt(hp + (long)(brow + r) * HH + hc0 + l15, o_ * tanhf(c));
            }
            vm_drain();  // this wave's 16 rows are at MALL
            if (flag && lane == 0) {
                __hip_atomic_store(&gflag[jj * 2 + mt], (unsigned)(t + 1),
                                   __ATOMIC_RELAXED, __HIP_MEMORY_SCOPE_AGENT);
            }
        }
    };

    // ---- t = 0: A = h0b (K=512), B = Whh ----
    ldxg(0);
    __syncthreads();  // Bs staged
    {
        f32x4 acc[4] = {};
        rec_mm<PP>(h0b + (long)bt * PP, Bs, acc, l15, quad, mt, kh);
        finish(acc, 0, true);
    }
    // Restage B for t>=1: Wcomb rows (bf16, K=1024). (Bs reads of t=0 completed
    // before finish's internal barrier; kh0 waves only touch red/global after it.)
    for (int ch = tid; ch < 64 * 128; ch += 256) {
        int row = ch >> 7, koff = (ch & 127) * 8;
        long wr = (long)(row >> 4) * HH + hc0 + (row & 15);
        *(bf16x8*)&Bs[row * BSTRIDE + koff] = *(const bf16x8*)&Wcomb[wr * HH + koff];
    }
    __syncthreads();

    // ---- main loop ----
    for (int t = 1; t < TS; ++t) {
        ldxg(t);  // independent of the wait: hides xg HBM latency under the spin
        if (tid < 2 * WPG) {
            const unsigned want = (unsigned)t;
            while (__hip_atomic_load(&gflag[tid], __ATOMIC_RELAXED, __HIP_MEMORY_SCOPE_AGENT) < want)
                __builtin_amdgcn_s_sleep(1);
        }
        __syncthreads();  // all waves see group's h(t-1) published; also orders red WAR
        f32x4 acc[4] = {};
        rec_mm<HH>(hfull + ((long)(t - 1) * BB + bt) * HH, Bs, acc, l15, quad, mt, kh);
        finish(acc, t, t < TS - 1);
    }

    if (kh == 0) {
#pragma unroll
        for (int r = 0; r < 4; ++r) cT[(long)(brow + r) * HH + hc0 + l15] = creg[r];
    }
}

// h0 cast to bf16; Whr transpose (fp32); zero the barrier flags.
__global__ __launch_bounds__(256) void prep_k(const float* __restrict__ h0,
                                              __hip_bfloat16* __restrict__ h0b,
                                              const float* __restrict__ Whr,
                                              float* __restrict__ WhrT,
                                              unsigned* __restrict__ flags) {
    int i = blockIdx.x * 256 + threadIdx.x;
    if (i < 2 * NWG) flags[i] = 0u;
    if (i < BB * PP) h0b[i] = __float2bfloat16(h0[i]);
    if (i < PP * HH) {
        int h = i / PP, p = i % PP;
        WhrT[i] = Whr[(long)p * HH + h];
    }
}

__global__ __launch_bounds__(256) void tail_k(const float* __restrict__ ys_last,
                                              float* __restrict__ hT) {
    int i = blockIdx.x * 256 + threadIdx.x;
    hT[i] = ys_last[i];
}

extern "C" void kernel_launch(void* const* d_in, const int* in_sizes, int n_in,
                              void* d_out, int out_size, void* d_ws, size_t ws_size,
                              hipStream_t stream) {
    const float* x   = (const float*)d_in[0];  // [T,B,I]
    const float* h0  = (const float*)d_in[1];  // [1,B,P]
    const float* c0  = (const float*)d_in[2];  // [1,B,H]
    const float* Wih = (const float*)d_in[3];  // [4H,I]
    const float* Whh = (const float*)d_in[4];  // [4H,P]
    const float* Whr = (const float*)d_in[5];  // [P,H]

    float* out = (float*)d_out;
    float* ys = out;                           // [T,B,P]
    float* hT = out + (long)TS * BB * PP;      // [B,P]
    float* cT = hT + (long)BB * PP;            // [B,H]

    char* ws = (char*)d_ws;
    size_t off = 0;
    __hip_bfloat16* xg = (__hip_bfloat16*)(ws + off);    off += (size_t)TS * BB * GG * 2;
    __hip_bfloat16* hfull = (__hip_bfloat16*)(ws + off); off += (size_t)TS * BB * HH * 2;
    __hip_bfloat16* Wcomb = (__hip_bfloat16*)(ws + off); off += (size_t)GG * HH * 2;
    float* WhrT = (float*)(ws + off);                    off += (size_t)HH * PP * 4;
    __hip_bfloat16* h0b = (__hip_bfloat16*)(ws + off);   off += (size_t)BB * PP * 2;
    unsigned* flags = (unsigned*)(ws + off);             off += 4096;

    static int smem_inited = 0;
    if (!smem_inited) {
        (void)hipFuncSetAttribute(reinterpret_cast<const void*>(lstm_rec_k),
                                  hipFuncAttributeMaxDynamicSharedMemorySize, SMEM_BYTES);
        smem_inited = 1;
    }

    dim3 blk(256);

    // prep: h0 -> bf16, Whr -> WhrT, zero flags
    prep_k<<<dim3((PP * HH) / 256), blk, 0, stream>>>(h0, h0b, Whr, WhrT, flags);

    // xg[T*B, 4H] = x @ W_ih^T
    mfma_gemm_bt<float, float, __hip_bfloat16>
        <<<dim3(GG / 128, (TS * BB) / 128), blk, 0, stream>>>(x, Wih, xg, TS * BB, GG, II);

    // W_comb[4H, H] = W_hh @ W_hr
    mfma_gemm_bt<float, float, __hip_bfloat16>
        <<<dim3(HH / 128, GG / 128), blk, 0, stream>>>(Whh, WhrT, Wcomb, GG, HH, PP);

    // full recurrence (cooperative launch for co-residency; group flag barriers inside)
    {
        const __hip_bfloat16* a0 = h0b;
        const float* a1 = c0;
        const float* a2 = Whh;
        const __hip_bfloat16* a3 = Wcomb;
        const __hip_bfloat16* a4 = xg;
        __hip_bfloat16* a5 = hfull;
        float* a6 = cT;
        unsigned* a7 = flags;
        void* args[] = {(void*)&a0, (void*)&a1, (void*)&a2, (void*)&a3,
                        (void*)&a4, (void*)&a5, (void*)&a6, (void*)&a7};
        (void)hipLaunchCooperativeKernel(reinterpret_cast<void*>(lstm_rec_k),
                                         dim3(NWG), blk, args, SMEM_BYTES, stream);
    }

    // ys[T*B, P] = hfull @ W_hr^T
    mfma_gemm_bt<__hip_bfloat16, float, float>
        <<<dim3(PP / 128, (TS * BB) / 128), blk, 0, stream>>>(hfull, Whr, ys, TS * BB, PP, HH);

    // hT = ys[T-1]
    tail_k<<<dim3((BB * PP) / 256), blk, 0, stream>>>(ys + (long)(TS - 1) * BB * PP, hT);
}

// Round 4
// 2813.454 us; speedup vs baseline: 1.0784x; 1.0784x over previous
//
#include <hip/hip_runtime.h>
#include <hip/hip_bf16.h>

#define TS 256
#define BB 128
#define II 1024
#define HH 1024
#define PP 512
#define GG 4096  // 4*H
#define NWG 256
#define WPG 64        // WGs per group (hidden tiles)
#define BT 32         // batch rows per group
#define HCW 16        // hidden cols per WG
#define BSTRIDE 1032  // shorts per Bs row (pad 1024+8 to spread banks)
#define RSTRIDE 20    // floats per red row (pad 16+4)
#define SMEM_BYTES (64 * BSTRIDE * 2 + 2 * 64 * RSTRIDE * 4)  // 132096 + 10240 = 142336

typedef __attribute__((ext_vector_type(8))) short bf16x8;
typedef __attribute__((ext_vector_type(4))) float f32x4;

__device__ __forceinline__ short f2bs(float f) {
    __hip_bfloat16 h = __float2bfloat16(f);
    return __builtin_bit_cast(short, h);
}
__device__ __forceinline__ float bs2f(short s) {
    return __bfloat162float(__builtin_bit_cast(__hip_bfloat16, s));
}

__device__ __forceinline__ bf16x8 ld8(const __hip_bfloat16* p) {
    return *(const bf16x8*)p;
}
__device__ __forceinline__ bf16x8 ld8(const float* p) {
    f32x4 lo = *(const f32x4*)p;
    f32x4 hi = *(const f32x4*)(p + 4);
    bf16x8 r;
#pragma unroll
    for (int i = 0; i < 4; ++i) { r[i] = f2bs(lo[i]); r[4 + i] = f2bs(hi[i]); }
    return r;
}

__device__ __forceinline__ void stv(float* p, long i, float v) { p[i] = v; }
__device__ __forceinline__ void stv(__hip_bfloat16* p, long i, float v) { p[i] = __float2bfloat16(v); }

// Agent-visible bf16 store: sc1 -> bypasses/streams past per-XCD L2, lands at the
// device coherence point (MALL). (Either sc1 decoding — agent scope or legacy-SLC
// stream — reaches >= MALL, so cross-XCD visibility is preserved; if it's agent
// scope, the ack is at MALL rather than HBM -> shorter drain.)
__device__ __forceinline__ void st_bf16_wt(__hip_bfloat16* p, float v) {
    int si = (int)f2bs(v);
    asm volatile("global_store_short %0, %1, off sc1" :: "v"(p), "v"(si));
}
// Coherence-point 16B load (skip stale per-XCD L2): reads >= MALL.
__device__ __forceinline__ f32x4 ld16_mall(const void* p) {
    f32x4 r;
    asm volatile("global_load_dwordx4 %0, %1, off sc1" : "=&v"(r) : "v"(p));
    return r;
}
// Per-wave drain: all outstanding vmem ops (incl. asm write-through stores) complete.
__device__ __forceinline__ void vm_drain() {
    asm volatile("s_waitcnt vmcnt(0)" ::: "memory");
}

// C[M,N] = A[M,K] @ B[N,K]^T, MFMA bf16. 128x128 tile, BK=32, 4 waves (64x64 each).
template <typename AT, typename BT_, typename CT>
__global__ __launch_bounds__(256) void mfma_gemm_bt(const AT* __restrict__ A,
                                                    const BT_* __restrict__ B,
                                                    CT* __restrict__ C,
                                                    int M, int N, int K) {
    __shared__ __align__(16) short As[128][40];
    __shared__ __align__(16) short Bsh[128][40];
    const int tid = threadIdx.x;
    const long bm = (long)blockIdx.y * 128;
    const long bn = (long)blockIdx.x * 128;
    const int lane = tid & 63, wv = tid >> 6;
    const int l15 = lane & 15, quad = lane >> 4;
    const int wm = (wv >> 1) * 64, wn = (wv & 1) * 64;
    f32x4 acc[4][4] = {};
    for (int k0 = 0; k0 < K; k0 += 32) {
#pragma unroll
        for (int i = 0; i < 2; ++i) {
            int ch = tid + 256 * i;
            int row = ch >> 2, koff = (ch & 3) * 8;
            *(bf16x8*)&As[row][koff] = ld8(&A[(bm + row) * (long)K + k0 + koff]);
            *(bf16x8*)&Bsh[row][koff] = ld8(&B[(bn + row) * (long)K + k0 + koff]);
        }
        __syncthreads();
        bf16x8 af[4], bfv[4];
#pragma unroll
        for (int t = 0; t < 4; ++t) {
            af[t] = *(const bf16x8*)&As[wm + t * 16 + l15][quad * 8];
            bfv[t] = *(const bf16x8*)&Bsh[wn + t * 16 + l15][quad * 8];
        }
#pragma unroll
        for (int mt = 0; mt < 4; ++mt)
#pragma unroll
            for (int nt = 0; nt < 4; ++nt)
                acc[mt][nt] = __builtin_amdgcn_mfma_f32_16x16x32_bf16(af[mt], bfv[nt], acc[mt][nt], 0, 0, 0);
        __syncthreads();
    }
#pragma unroll
    for (int mt = 0; mt < 4; ++mt)
#pragma unroll
        for (int nt = 0; nt < 4; ++nt)
#pragma unroll
            for (int r = 0; r < 4; ++r) {
                long row = bm + wm + mt * 16 + quad * 4 + r;
                long col = bn + wn + nt * 16 + l15;
                stv(C, row * N + col, acc[mt][nt][r]);
            }
}

// Per-wave matmul slice of the recurrence:
//   out[32 batch x 64 gatecols] = A[32 x K] @ Bs[64 x K]^T, waves split (mt, K-half).
// Bs rows ordered [gate g 0..3][hcol h 0..15]; acc[g] = gate g at col l15.
// A loads: ALL issued upfront as coherence-point (sc1) asm loads, then one
// vmcnt(0) + sched_barrier(0), then pure-register MFMA (single latency exposure).
template <int K>
__device__ __forceinline__ void rec_mm(const __hip_bfloat16* __restrict__ Abase,
                                       const short* __restrict__ Bs, f32x4* acc,
                                       int l15, int quad, int mt, int kh) {
    constexpr int KH = K / 2;
    constexpr int NI = KH / 32;
    const __hip_bfloat16* ap = Abase + (long)(mt * 16 + l15) * K + kh * KH + quad * 8;
    const short* bp0 = Bs + l15 * BSTRIDE + kh * KH + quad * 8;
    f32x4 avr[NI];
#pragma unroll
    for (int i = 0; i < NI; ++i) avr[i] = ld16_mall(ap + i * 32);
    asm volatile("s_waitcnt vmcnt(0)" ::: "memory");
    __builtin_amdgcn_sched_barrier(0);
#pragma unroll
    for (int i = 0; i < NI; ++i) {
        bf16x8 av = __builtin_bit_cast(bf16x8, avr[i]);
        const short* bp = bp0 + i * 32;
        acc[0] = __builtin_amdgcn_mfma_f32_16x16x32_bf16(av, *(const bf16x8*)(bp), acc[0], 0, 0, 0);
        acc[1] = __builtin_amdgcn_mfma_f32_16x16x32_bf16(av, *(const bf16x8*)(bp + 16 * BSTRIDE), acc[1], 0, 0, 0);
        acc[2] = __builtin_amdgcn_mfma_f32_16x16x32_bf16(av, *(const bf16x8*)(bp + 32 * BSTRIDE), acc[2], 0, 0, 0);
        acc[3] = __builtin_amdgcn_mfma_f32_16x16x32_bf16(av, *(const bf16x8*)(bp + 48 * BSTRIDE), acc[3], 0, 0, 0);
    }
}

// Cooperative recurrence: 4 independent batch-groups x 64 WGs.
// WG = (grp = wg>>6, jj = wg&63): batch rows [32*grp, +32), hidden cols [16*jj, +16).
// Protocol (fence-free, per-WAVE decoupled):
//   release: write-through hfull stores (sc1) -> per-wave vmcnt drain ->
//            per-wave flag store (flags[grp][mt][jj], value t+1).
//   acquire: each consumer wave spins ONLY on its 32 producer flags
//            (flags[grp][mt][kh*32 .. +32), one 64-lane load + __all) ->
//            A reads are sc1 coherence-point loads. No block-wide join
//            before compute; kh-halves proceed independently.
__global__ __launch_bounds__(256) void lstm_rec_k(
    const __hip_bfloat16* __restrict__ h0b,   // [128][512]
    const float* __restrict__ c0,             // [128][1024]
    const float* __restrict__ Whh,            // [4096][512] fp32
    const __hip_bfloat16* __restrict__ Wcomb, // [4096][1024]
    const __hip_bfloat16* __restrict__ xg,    // [256][128][4096]
    __hip_bfloat16* __restrict__ hfull,       // [256][128][1024]
    float* __restrict__ cT,                   // [128][1024]
    unsigned* __restrict__ flags) {           // [4][2][64]
    extern __shared__ char smem[];
    short* Bs = (short*)smem;                        // [64][BSTRIDE] bf16
    float* red = (float*)(smem + 64 * BSTRIDE * 2);  // [2][64][RSTRIDE] K-split partials

    const int tid = threadIdx.x;
    const int wg = blockIdx.x;
    const int grp = wg >> 6;
    const int jj = wg & 63;
    const int hc0 = jj * HCW;
    const int bt = grp * BT;
    const int lane = tid & 63, wv = tid >> 6;
    const int l15 = lane & 15, quad = lane >> 4;
    const int mt = wv & 1, kh = wv >> 1;
    unsigned* gflag = flags + grp * (2 * WPG);       // [2][64] for this group
    const int brow = bt + mt * 16 + quad * 4;        // + r

    // Stage B(t=0): 64 rows (g*16+h) = Whh[g*1024 + hc0 + h][0..512), fp32 -> bf16
    for (int ch = tid; ch < 64 * 64; ch += 256) {
        int row = ch >> 6, koff = (ch & 63) * 8;
        long wr = (long)(row >> 4) * HH + hc0 + (row & 15);
        *(bf16x8*)&Bs[row * BSTRIDE + koff] = ld8(&Whh[wr * PP + koff]);
    }

    float creg[4];
    if (kh == 0) {
#pragma unroll
        for (int r = 0; r < 4; ++r) creg[r] = c0[(long)(brow + r) * HH + hc0 + l15];
    }

    short xr[16];
    auto ldxg = [&](int t) {  // prefetch xg for this step (issued before the flag wait)
        if (kh == 0) {
            const __hip_bfloat16* xgt = xg + (long)t * BB * GG;
#pragma unroll
            for (int g = 0; g < 4; ++g)
#pragma unroll
                for (int r = 0; r < 4; ++r)
                    xr[g * 4 + r] = *(const short*)(xgt + (long)(brow + r) * GG + g * HH + hc0 + l15);
        }
    };

    // Per-wave spin: this wave's 32 producer flags (contiguous), all >= want.
    // All 64 lanes load 32 flags (2 lanes per flag, broadcast) -> one memory op.
    auto wave_wait = [&](int want) {
        const unsigned* fp = gflag + mt * WPG + kh * 32;
        for (;;) {
            unsigned v = __hip_atomic_load(&fp[lane & 31], __ATOMIC_RELAXED,
                                           __HIP_MEMORY_SCOPE_AGENT);
            if (__all((int)(v >= (unsigned)want))) break;
            __builtin_amdgcn_s_sleep(1);
        }
    };

    // K-split reduce + in-register cell + per-wave release (drain + own flag).
    auto finish = [&](f32x4* acc, int t, bool flag) {
        if (kh == 1) {
            float* rp = red + (mt * 64 + lane) * RSTRIDE;
#pragma unroll
            for (int g = 0; g < 4; ++g) *(f32x4*)(rp + g * 4) = acc[g];
        }
        __syncthreads();
        if (kh == 0) {
            const float* rp = red + (mt * 64 + lane) * RSTRIDE;
#pragma unroll
            for (int g = 0; g < 4; ++g) acc[g] += *(const f32x4*)(rp + g * 4);
            __hip_bfloat16* hp = hfull + (long)t * BB * HH;
#pragma unroll
            for (int r = 0; r < 4; ++r) {
                float gi = acc[0][r] + bs2f(xr[r]);
                float gf = acc[1][r] + bs2f(xr[4 + r]);
                float gg = acc[2][r] + bs2f(xr[8 + r]);
                float go = acc[3][r] + bs2f(xr[12 + r]);
                float i_ = 1.f / (1.f + expf(-gi));
                float f_ = 1.f / (1.f + expf(-gf));
                float g_ = tanhf(gg);
                float o_ = 1.f / (1.f + expf(-go));
                float c = f_ * creg[r] + i_ * g_;
                creg[r] = c;
                st_bf16_wt(hp + (long)(brow + r) * HH + hc0 + l15, o_ * tanhf(c));
            }
            vm_drain();  // this wave's 16 rows are at the coherence point
            if (flag && lane == 0) {
                __hip_atomic_store(&gflag[mt * WPG + jj], (unsigned)(t + 1),
                                   __ATOMIC_RELAXED, __HIP_MEMORY_SCOPE_AGENT);
            }
        }
    };

    // ---- t = 0: A = h0b (K=512), B = Whh ----
    ldxg(0);
    __syncthreads();  // Bs staged
    {
        f32x4 acc[4] = {};
        rec_mm<PP>(h0b + (long)bt * PP, Bs, acc, l15, quad, mt, kh);
        finish(acc, 0, true);
    }
    // Restage B for t>=1: Wcomb rows (bf16, K=1024). (Bs reads of t=0 completed
    // before finish's internal barrier; kh0 waves only touch red/global after it.)
    for (int ch = tid; ch < 64 * 128; ch += 256) {
        int row = ch >> 7, koff = (ch & 127) * 8;
        long wr = (long)(row >> 4) * HH + hc0 + (row & 15);
        *(bf16x8*)&Bs[row * BSTRIDE + koff] = *(const bf16x8*)&Wcomb[wr * HH + koff];
    }
    __syncthreads();

    // ---- main loop ----
    for (int t = 1; t < TS; ++t) {
        ldxg(t);        // issued before the spin: xg latency hides under the wait
        wave_wait(t);   // per-wave: only this wave's 32 producers
        f32x4 acc[4] = {};
        rec_mm<HH>(hfull + ((long)(t - 1) * BB + bt) * HH, Bs, acc, l15, quad, mt, kh);
        finish(acc, t, t < TS - 1);
        // finish's internal __syncthreads orders the red-buffer WAR across waves.
    }

    if (kh == 0) {
#pragma unroll
        for (int r = 0; r < 4; ++r) cT[(long)(brow + r) * HH + hc0 + l15] = creg[r];
    }
}

// h0 cast to bf16; Whr transpose (fp32); zero the barrier flags.
__global__ __launch_bounds__(256) void prep_k(const float* __restrict__ h0,
                                              __hip_bfloat16* __restrict__ h0b,
                                              const float* __restrict__ Whr,
                                              float* __restrict__ WhrT,
                                              unsigned* __restrict__ flags) {
    int i = blockIdx.x * 256 + threadIdx.x;
    if (i < 2 * NWG) flags[i] = 0u;
    if (i < BB * PP) h0b[i] = __float2bfloat16(h0[i]);
    if (i < PP * HH) {
        int h = i / PP, p = i % PP;
        WhrT[i] = Whr[(long)p * HH + h];
    }
}

__global__ __launch_bounds__(256) void tail_k(const float* __restrict__ ys_last,
                                              float* __restrict__ hT) {
    int i = blockIdx.x * 256 + threadIdx.x;
    hT[i] = ys_last[i];
}

extern "C" void kernel_launch(void* const* d_in, const int* in_sizes, int n_in,
                              void* d_out, int out_size, void* d_ws, size_t ws_size,
                              hipStream_t stream) {
    const float* x   = (const float*)d_in[0];  // [T,B,I]
    const float* h0  = (const float*)d_in[1];  // [1,B,P]
    const float* c0  = (const float*)d_in[2];  // [1,B,H]
    const float* Wih = (const float*)d_in[3];  // [4H,I]
    const float* Whh = (const float*)d_in[4];  // [4H,P]
    const float* Whr = (const float*)d_in[5];  // [P,H]

    float* out = (float*)d_out;
    float* ys = out;                           // [T,B,P]
    float* hT = out + (long)TS * BB * PP;      // [B,P]
    float* cT = hT + (long)BB * PP;            // [B,H]

    char* ws = (char*)d_ws;
    size_t off = 0;
    __hip_bfloat16* xg = (__hip_bfloat16*)(ws + off);    off += (size_t)TS * BB * GG * 2;
    __hip_bfloat16* hfull = (__hip_bfloat16*)(ws + off); off += (size_t)TS * BB * HH * 2;
    __hip_bfloat16* Wcomb = (__hip_bfloat16*)(ws + off); off += (size_t)GG * HH * 2;
    float* WhrT = (float*)(ws + off);                    off += (size_t)HH * PP * 4;
    __hip_bfloat16* h0b = (__hip_bfloat16*)(ws + off);   off += (size_t)BB * PP * 2;
    unsigned* flags = (unsigned*)(ws + off);             off += 4096;

    static int smem_inited = 0;
    if (!smem_inited) {
        (void)hipFuncSetAttribute(reinterpret_cast<const void*>(lstm_rec_k),
                                  hipFuncAttributeMaxDynamicSharedMemorySize, SMEM_BYTES);
        smem_inited = 1;
    }

    dim3 blk(256);

    // prep: h0 -> bf16, Whr -> WhrT, zero flags
    prep_k<<<dim3((PP * HH) / 256), blk, 0, stream>>>(h0, h0b, Whr, WhrT, flags);

    // xg[T*B, 4H] = x @ W_ih^T
    mfma_gemm_bt<float, float, __hip_bfloat16>
        <<<dim3(GG / 128, (TS * BB) / 128), blk, 0, stream>>>(x, Wih, xg, TS * BB, GG, II);

    // W_comb[4H, H] = W_hh @ W_hr
    mfma_gemm_bt<float, float, __hip_bfloat16>
        <<<dim3(HH / 128, GG / 128), blk, 0, stream>>>(Whh, WhrT, Wcomb, GG, HH, PP);

    // full recurrence (cooperative launch for co-residency; group flag barriers inside)
    {
        const __hip_bfloat16* a0 = h0b;
        const float* a1 = c0;
        const float* a2 = Whh;
        const __hip_bfloat16* a3 = Wcomb;
        const __hip_bfloat16* a4 = xg;
        __hip_bfloat16* a5 = hfull;
        float* a6 = cT;
        unsigned* a7 = flags;
        void* args[] = {(void*)&a0, (void*)&a1, (void*)&a2, (void*)&a3,
                        (void*)&a4, (void*)&a5, (void*)&a6, (void*)&a7};
        (void)hipLaunchCooperativeKernel(reinterpret_cast<void*>(lstm_rec_k),
                                         dim3(NWG), blk, args, SMEM_BYTES, stream);
    }

    // ys[T*B, P] = hfull @ W_hr^T
    mfma_gemm_bt<__hip_bfloat16, float, float>
        <<<dim3(PP / 128, (TS * BB) / 128), blk, 0, stream>>>(hfull, Whr, ys, TS * BB, PP, HH);

    // hT = ys[T-1]
    tail_k<<<dim3((BB * PP) / 256), blk, 0, stream>>>(ys + (long)(TS - 1) * BB * PP, hT);
}